// Round 3
// baseline (13212.926 us; speedup 1.0000x reference)
//
#include <hip/hip_runtime.h>
#include <hip/hip_bf16.h>
#include <stdint.h>

#define HID 768
#define COND 1280
#define NB 256
#define VOC 128
#define TSTEPS 64
#define KTOP 40
#define G3 2304              // 3*HID
#define LH (NB*HID)          // per-layer hidden elems

// ---------------- Threefry2x32 (exact JAX semantics) ----------------
__device__ __forceinline__ uint32_t rotl32(uint32_t v, int d) {
  return (v << d) | (v >> (32 - d));
}

__device__ __forceinline__ void threefry(uint32_t k0, uint32_t k1,
                                         uint32_t x0, uint32_t x1,
                                         uint32_t& o0, uint32_t& o1) {
  uint32_t k2 = k0 ^ k1 ^ 0x1BD11BDAu;
  x0 += k0; x1 += k1;
#define TF_R(r) { x0 += x1; x1 = rotl32(x1, r); x1 ^= x0; }
  TF_R(13) TF_R(15) TF_R(26) TF_R(6)
  x0 += k1; x1 += k2 + 1u;
  TF_R(17) TF_R(29) TF_R(16) TF_R(24)
  x0 += k2; x1 += k0 + 2u;
  TF_R(13) TF_R(15) TF_R(26) TF_R(6)
  x0 += k0; x1 += k1 + 3u;
  TF_R(17) TF_R(29) TF_R(16) TF_R(24)
  x0 += k1; x1 += k2 + 4u;
  TF_R(13) TF_R(15) TF_R(26) TF_R(6)
  x0 += k2; x1 += k0 + 5u;
#undef TF_R
  o0 = x0; o1 = x1;
}

__device__ __forceinline__ float bits_to_01(uint32_t b) {
  return __uint_as_float((b >> 9) | 0x3f800000u) - 1.0f;
}

__device__ __forceinline__ float gelu_exact(float x) {
  // x * (erf(x/sqrt(2)) + 1) / 2
  return x * (erff(x / 0x1.6a09e6p+0f) + 1.0f) * 0.5f;
}

__device__ __forceinline__ float sigmoid_(float x) {
  return 0.5f + 0.5f * tanhf(0.5f * x);   // XLA logistic expansion
}

// ---- init: cur=1, seq[:,0]=1; partitionable split: key_t = threefry(key, (0,t)) ----
__global__ __launch_bounds__(256) void k_init(uint32_t* keys, int* cur, int* seq) {
  int tid = threadIdx.x;
  cur[tid] = 1;
  seq[tid * (TSTEPS + 1)] = 1;
  if (tid < 64) {
    uint32_t o0, o1;
    threefry(0u, 7u, 0u, (uint32_t)tid, o0, o1);
    keys[2 * tid] = o0; keys[2 * tid + 1] = o1;
  }
}

// ---- z = normal(key(42), (256,768)); partitionable bits: xor of block output ----
__global__ __launch_bounds__(256) void k_z(float* __restrict__ z) {
  int i = blockIdx.x * 256 + threadIdx.x;   // 0..196607
  uint32_t o0, o1;
  threefry(0u, 42u, 0u, (uint32_t)i, o0, o1);
  uint32_t bits = o0 ^ o1;
  const float SQ2 = 0x1.6a09e6p+0f;
  const float NM1 = -0x1.fffffep-1f;        // nextafter(-1,0)
  float f = bits_to_01(bits);
  float u = fmaxf(NM1, f * 2.0f + NM1);
  z[i] = SQ2 * erfinvf(u);
}

// ---------------- pe-dependent precomputes (dots over COND=1280) ----------------
__global__ __launch_bounds__(256) void k_pe1(const float* __restrict__ p,
    const float* __restrict__ Wd, const float* __restrict__ Wih0,
    const float* __restrict__ Wf1, const float* __restrict__ bf1,
    float* __restrict__ cd, float* __restrict__ c0, float* __restrict__ t1) {
  int g = blockIdx.x, tid = threadIdx.x;
  const float* row;
  if (g < HID)            row = Wd   + (size_t)g * 2048 + HID;
  else if (g < HID + G3)  row = Wih0 + (size_t)(g - HID) * 2048 + HID;
  else                    row = Wf1  + (size_t)(g - HID - G3) * COND;
  float acc = 0.0f;
  for (int k = tid; k < COND; k += 256) acc += p[k] * row[k];
  __shared__ float red[256];
  red[tid] = acc; __syncthreads();
  for (int s = 128; s > 0; s >>= 1) { if (tid < s) red[tid] += red[tid + s]; __syncthreads(); }
  if (tid == 0) {
    if (g < HID) cd[g] = red[0];
    else if (g < HID + G3) c0[g - HID] = red[0];
    else { int j = g - HID - G3; t1[j] = gelu_exact(red[0] + bf1[j]); }
  }
}

__global__ __launch_bounds__(256) void k_pe2(const float* __restrict__ t1,
    const float* __restrict__ Wf2, const float* __restrict__ bf2,
    float* __restrict__ gamma, float* __restrict__ beta) {
  int j = blockIdx.x, tid = threadIdx.x;
  const float* row = Wf2 + (size_t)j * HID;
  float acc = 0.0f;
  for (int k = tid; k < HID; k += 256) acc += t1[k] * row[k];
  __shared__ float red[256];
  red[tid] = acc; __syncthreads();
  for (int s = 128; s > 0; s >>= 1) { if (tid < s) red[tid] += red[tid + s]; __syncthreads(); }
  if (tid == 0) {
    float v = red[0] + bf2[j];
    if (j < HID) gamma[j] = v; else beta[j - HID] = v;
  }
}

// ---------------- generic fp32 GEMM: C[m][n] = sum_k A[m][k]*B[n][k] ----------------
template<bool FILM, int EPI>
__global__ __launch_bounds__(256) void k_gemm(
    const float* __restrict__ A, int lda,
    const float* __restrict__ B, int ldb,
    float* __restrict__ C, int N, int Kp, long partStride,
    const float* __restrict__ ga, const float* __restrict__ be,
    const float* __restrict__ e0, const float* __restrict__ e1,
    float* __restrict__ H1, float* __restrict__ H2) {
  __shared__ __align__(16) float As[32][68];
  __shared__ __align__(16) float Bs[32][68];
  const int tid = threadIdx.x;
  const int tm = tid & 15, tn = tid >> 4;
  const int bm = blockIdx.x * 64, bn = blockIdx.y * 64;
  const int kbase = blockIdx.z * Kp;
  const int lr = tid >> 3;          // 0..31
  const int lk = (tid & 7) * 4;     // 0,4,..,28
  float acc[4][4] = {};
  for (int k0 = 0; k0 < Kp; k0 += 32) {
    int gk = kbase + k0 + lk;
    float4 av0 = *(const float4*)(A + (size_t)(bm + lr)      * lda + gk);
    float4 av1 = *(const float4*)(A + (size_t)(bm + lr + 32) * lda + gk);
    float4 bv0 = *(const float4*)(B + (size_t)(bn + lr)      * ldb + gk);
    float4 bv1 = *(const float4*)(B + (size_t)(bn + lr + 32) * ldb + gk);
    if (FILM) {
      float4 g = *(const float4*)(ga + gk);
      float4 bb = *(const float4*)(be + gk);
      av0.x = av0.x * (1.0f + g.x) + bb.x; av0.y = av0.y * (1.0f + g.y) + bb.y;
      av0.z = av0.z * (1.0f + g.z) + bb.z; av0.w = av0.w * (1.0f + g.w) + bb.w;
      av1.x = av1.x * (1.0f + g.x) + bb.x; av1.y = av1.y * (1.0f + g.y) + bb.y;
      av1.z = av1.z * (1.0f + g.z) + bb.z; av1.w = av1.w * (1.0f + g.w) + bb.w;
    }
    __syncthreads();
    As[lk + 0][lr] = av0.x; As[lk + 1][lr] = av0.y; As[lk + 2][lr] = av0.z; As[lk + 3][lr] = av0.w;
    As[lk + 0][lr + 32] = av1.x; As[lk + 1][lr + 32] = av1.y; As[lk + 2][lr + 32] = av1.z; As[lk + 3][lr + 32] = av1.w;
    Bs[lk + 0][lr] = bv0.x; Bs[lk + 1][lr] = bv0.y; Bs[lk + 2][lr] = bv0.z; Bs[lk + 3][lr] = bv0.w;
    Bs[lk + 0][lr + 32] = bv1.x; Bs[lk + 1][lr + 32] = bv1.y; Bs[lk + 2][lr + 32] = bv1.z; Bs[lk + 3][lr + 32] = bv1.w;
    __syncthreads();
#pragma unroll
    for (int kk = 0; kk < 32; kk++) {
      float4 a = *(const float4*)&As[kk][tm * 4];
      float4 b = *(const float4*)&Bs[kk][tn * 4];
      acc[0][0] += a.x * b.x; acc[0][1] += a.x * b.y; acc[0][2] += a.x * b.z; acc[0][3] += a.x * b.w;
      acc[1][0] += a.y * b.x; acc[1][1] += a.y * b.y; acc[1][2] += a.y * b.z; acc[1][3] += a.y * b.w;
      acc[2][0] += a.z * b.x; acc[2][1] += a.z * b.y; acc[2][2] += a.z * b.z; acc[2][3] += a.z * b.w;
      acc[3][0] += a.w * b.x; acc[3][1] += a.w * b.y; acc[3][2] += a.w * b.z; acc[3][3] += a.w * b.w;
    }
  }
  if (EPI == 0) {
    float* Cp = C + (size_t)blockIdx.z * (size_t)partStride;
#pragma unroll
    for (int i = 0; i < 4; i++) {
      float4 v; v.x = acc[i][0]; v.y = acc[i][1]; v.z = acc[i][2]; v.w = acc[i][3];
      *(float4*)(Cp + (size_t)(bm + tm * 4 + i) * N + bn + tn * 4) = v;
    }
  } else {
#pragma unroll
    for (int i = 0; i < 4; i++)
#pragma unroll
      for (int j = 0; j < 4; j++) {
        int row = bm + tm * 4 + i, col = bn + tn * 4 + j;
        float v = gelu_exact(acc[i][j] + e0[col] + e1[col]);
        C [(size_t)row * N + col] = v;
        H1[(size_t)row * N + col] = v;
        H2[(size_t)row * N + col] = v;
      }
  }
}

// ---------------- GRU gates (sums split-K partials; L0 uses E0 gather) ----------------
template<bool L0>
__global__ __launch_bounds__(256) void k_gates(
    const float* __restrict__ gxP, const float* __restrict__ ghP,
    const float* __restrict__ E0, const int* __restrict__ cur,
    const float* __restrict__ c0,
    const float* __restrict__ bih, const float* __restrict__ bhh,
    const float* __restrict__ hin, float* __restrict__ hout) {
  int idx = blockIdx.x * 256 + threadIdx.x;   // < 196608
  int b = idx / HID, j = idx - b * HID;
  const long S = (long)NB * G3;
  long base = (long)b * G3;
  float xr, xz, xn;
  if (L0) {
    const float* e = E0 + (size_t)cur[b] * G3;
    xr = e[j]           + c0[j]           + bih[j];
    xz = e[j + HID]     + c0[j + HID]     + bih[j + HID];
    xn = e[j + 2 * HID] + c0[j + 2 * HID] + bih[j + 2 * HID];
  } else {
    xr = gxP[base + j]           + gxP[S + base + j]           + bih[j];
    xz = gxP[base + j + HID]     + gxP[S + base + j + HID]     + bih[j + HID];
    xn = gxP[base + j + 2 * HID] + gxP[S + base + j + 2 * HID] + bih[j + 2 * HID];
  }
  float hr = ghP[base + j]           + ghP[S + base + j]           + bhh[j];
  float hz = ghP[base + j + HID]     + ghP[S + base + j + HID]     + bhh[j + HID];
  float hn = ghP[base + j + 2 * HID] + ghP[S + base + j + 2 * HID] + bhh[j + 2 * HID];
  float r  = sigmoid_(xr + hr);
  float zg = sigmoid_(xz + hz);
  float n  = tanhf(xn + r * hn);
  float h  = hin[idx];
  hout[idx] = (1.0f - zg) * n + zg * h;
}

// ---------------- logits + topk/topp + gumbel-argmax, one block per batch row ----------------
__global__ __launch_bounds__(256) void k_sample(
    const float* __restrict__ oP, const float* __restrict__ embW,
    const uint32_t* __restrict__ keys, int t,
    int* __restrict__ cur, int* __restrict__ seq) {
  const int b = blockIdx.x, tid = threadIdx.x;
  __shared__ __align__(16) float o[HID];
  __shared__ float logit[VOC];
  __shared__ float gum[VOC];
  __shared__ float prob[VOC];
  __shared__ float skey[VOC];
  __shared__ int   sidx[VOC];
  __shared__ float rv[VOC];
  __shared__ int   ri[VOC];
  __shared__ float sden;
  const long OS = (long)NB * HID;
  for (int k = tid; k < HID; k += 256) {
    long ix = (long)b * HID + k;
    o[k] = ((oP[ix] + oP[OS + ix]) + oP[2 * OS + ix]) + oP[3 * OS + ix];
  }
  __syncthreads();
  if (tid < VOC) {
    const float4* ew = (const float4*)(embW + (size_t)tid * HID);
    const float4* ov = (const float4*)o;
    float a0 = 0, a1 = 0, a2 = 0, a3 = 0;
#pragma unroll 4
    for (int q = 0; q < HID / 4; q++) {
      float4 w = ew[q]; float4 x = ov[q];
      a0 += w.x * x.x; a1 += w.y * x.y; a2 += w.z * x.z; a3 += w.w * x.w;
    }
    logit[tid] = (a0 + a1) + (a2 + a3);   // TEMP = 1
  } else {
    // gumbel bits: partitionable random_bits -> xor of threefry output words
    int v = tid - VOC;
    int i = b * VOC + v;                  // row-major (256,128)
    uint32_t o0, o1;
    uint32_t kk0 = keys[2 * t], kk1 = keys[2 * t + 1];
    threefry(kk0, kk1, 0u, (uint32_t)i, o0, o1);
    uint32_t bits = o0 ^ o1;
    float f = bits_to_01(bits);
    float u = f + 0x1p-126f;
    u = fmaxf(0x1p-126f, u);
    gum[v] = -logf(-logf(u));
  }
  __syncthreads();
  if (tid < VOC) { skey[tid] = logit[tid]; sidx[tid] = tid; }
  // sort #1: descending by logit (value only needed for kth/max; ties irrelevant)
  for (int ksz = 2; ksz <= VOC; ksz <<= 1) {
    for (int jsz = ksz >> 1; jsz > 0; jsz >>= 1) {
      __syncthreads();
      if (tid < VOC) {
        int ixj = tid ^ jsz;
        if (ixj > tid) {
          float ka = skey[tid], kb = skey[ixj];
          int ia = sidx[tid], ib = sidx[ixj];
          bool ab = (ka > kb) || (ka == kb && ia < ib);
          bool up = ((tid & ksz) == 0);
          if (up ? !ab : ab) {
            skey[tid] = kb; skey[ixj] = ka; sidx[tid] = ib; sidx[ixj] = ia;
          }
        }
      }
    }
  }
  __syncthreads();
  float m = skey[0], kth = skey[KTOP - 1];
  __syncthreads();
  if (tid < VOC) {
    float l = logit[tid];
    prob[tid] = (l < kth) ? 0.0f : expf(l - m);
  }
  __syncthreads();
  if (tid < VOC) rv[tid] = prob[tid];
  __syncthreads();
  for (int s = 64; s > 0; s >>= 1) { if (tid < s) rv[tid] += rv[tid + s]; __syncthreads(); }
  if (tid == 0) sden = rv[0];
  __syncthreads();
  if (tid < VOC) {
    prob[tid] = prob[tid] / sden;
    skey[tid] = prob[tid];                // sort #2 key: prob (matches argsort(-probs))
    sidx[tid] = tid;
  }
  for (int ksz = 2; ksz <= VOC; ksz <<= 1) {
    for (int jsz = ksz >> 1; jsz > 0; jsz >>= 1) {
      __syncthreads();
      if (tid < VOC) {
        int ixj = tid ^ jsz;
        if (ixj > tid) {
          float ka = skey[tid], kb = skey[ixj];
          int ia = sidx[tid], ib = sidx[ixj];
          bool ab = (ka > kb) || (ka == kb && ia < ib);
          bool up = ((tid & ksz) == 0);
          if (up ? !ab : ab) {
            skey[tid] = kb; skey[ixj] = ka; sidx[tid] = ib; sidx[ixj] = ia;
          }
        }
      }
    }
  }
  __syncthreads();
  if (tid == 0) {  // sequential top-p in sorted (prob desc, idx asc) order
    float c = 0.0f;
    for (int i2 = 0; i2 < VOC; i2++) {
      float pv = skey[i2];
      if (i2 > 0 && c > 0.9f) prob[sidx[i2]] = 0.0f;
      c += pv;
    }
  }
  __syncthreads();
  if (tid < VOC) { rv[tid] = logf(prob[tid]) + gum[tid]; ri[tid] = tid; }
  __syncthreads();
  for (int s = 64; s > 0; s >>= 1) {
    if (tid < s) {
      float vb = rv[tid + s]; int ib2 = ri[tid + s];
      if (vb > rv[tid] || (vb == rv[tid] && ib2 < ri[tid])) { rv[tid] = vb; ri[tid] = ib2; }
    }
    __syncthreads();
  }
  if (tid == 0) { int v = ri[0]; cur[b] = v; seq[b * (TSTEPS + 1) + t + 1] = v; }
}

// ---------------- launch ----------------
extern "C" void kernel_launch(void* const* d_in, const int* in_sizes, int n_in,
                              void* d_out, int out_size, void* d_ws, size_t ws_size,
                              hipStream_t stream) {
  const float* p    = (const float*)d_in[0];
  const float* embW = (const float*)d_in[1];
  const float* Wd   = (const float*)d_in[2];
  const float* bd   = (const float*)d_in[3];
  const float* Wih0 = (const float*)d_in[4];
  const float* Whh0 = (const float*)d_in[5];
  const float* bih0 = (const float*)d_in[6];
  const float* bhh0 = (const float*)d_in[7];
  const float* Wih1 = (const float*)d_in[8];
  const float* Whh1 = (const float*)d_in[9];
  const float* bih1 = (const float*)d_in[10];
  const float* bhh1 = (const float*)d_in[11];
  const float* Wih2 = (const float*)d_in[12];
  const float* Whh2 = (const float*)d_in[13];
  const float* bih2 = (const float*)d_in[14];
  const float* bhh2 = (const float*)d_in[15];
  const float* Wf1  = (const float*)d_in[16];
  const float* bf1  = (const float*)d_in[17];
  const float* Wf2  = (const float*)d_in[18];
  const float* bf2  = (const float*)d_in[19];
  const float* Wo   = (const float*)d_in[20];
  int* seq = (int*)d_out;

  float* w = (float*)d_ws;
  float* z     = w;                  // 196608
  float* E0    = z + 196608;         // 294912
  float* cd    = E0 + 294912;        // 768
  float* c0    = cd + 768;           // 2304
  float* t1    = c0 + 2304;          // 768
  float* gamma = t1 + 768;           // 768
  float* beta  = gamma + 768;        // 768
  float* HA    = beta + 768;         // 589824
  float* HB    = HA + 589824;        // 589824
  float* gxP   = HB + 589824;        // 1179648
  float* ghP   = gxP + 1179648;      // 1179648
  float* oP    = ghP + 1179648;      // 786432
  uint32_t* keys = (uint32_t*)(oP + 786432);
  int* cur = (int*)(keys + 128);

  const long PS_G = (long)NB * G3;
  const long PS_O = (long)NB * HID;

  k_init<<<1, 256, 0, stream>>>(keys, cur, seq);
  k_z<<<768, 256, 0, stream>>>(z);
  k_pe1<<<HID + G3 + HID, 256, 0, stream>>>(p, Wd, Wih0, Wf1, bf1, cd, c0, t1);
  k_pe2<<<2 * HID, 256, 0, stream>>>(t1, Wf2, bf2, gamma, beta);
  // E0 = emb_W @ Wih0[:, :768].T  -> [128, 2304]
  k_gemm<false, 0><<<dim3(2, 36, 1), 256, 0, stream>>>(embW, HID, Wih0, 2048, E0,
      G3, HID, 0L, nullptr, nullptr, nullptr, nullptr, nullptr, nullptr);
  // h0 = gelu(z @ Wd[:, :768].T + cd + bd) -> HA[0..2]
  k_gemm<false, 1><<<dim3(4, 12, 1), 256, 0, stream>>>(z, HID, Wd, 2048, HA,
      HID, HID, 0L, nullptr, nullptr, cd, bd, HA + LH, HA + 2 * LH);

  for (int t = 0; t < TSTEPS; t++) {
    float* Hin  = (t & 1) ? HB : HA;
    float* Hout = (t & 1) ? HA : HB;
    k_gemm<false, 0><<<dim3(4, 36, 2), 256, 0, stream>>>(Hin, HID, Whh0, HID, ghP,
        G3, 384, PS_G, nullptr, nullptr, nullptr, nullptr, nullptr, nullptr);
    k_gates<true><<<768, 256, 0, stream>>>(nullptr, ghP, E0, cur, c0, bih0, bhh0, Hin, Hout);
    k_gemm<false, 0><<<dim3(4, 36, 2), 256, 0, stream>>>(Hout, HID, Wih1, HID, gxP,
        G3, 384, PS_G, nullptr, nullptr, nullptr, nullptr, nullptr, nullptr);
    k_gemm<false, 0><<<dim3(4, 36, 2), 256, 0, stream>>>(Hin + LH, HID, Whh1, HID, ghP,
        G3, 384, PS_G, nullptr, nullptr, nullptr, nullptr, nullptr, nullptr);
    k_gates<false><<<768, 256, 0, stream>>>(gxP, ghP, nullptr, nullptr, nullptr,
        bih1, bhh1, Hin + LH, Hout + LH);
    k_gemm<false, 0><<<dim3(4, 36, 2), 256, 0, stream>>>(Hout + LH, HID, Wih2, HID, gxP,
        G3, 384, PS_G, nullptr, nullptr, nullptr, nullptr, nullptr, nullptr);
    k_gemm<false, 0><<<dim3(4, 36, 2), 256, 0, stream>>>(Hin + 2 * LH, HID, Whh2, HID, ghP,
        G3, 384, PS_G, nullptr, nullptr, nullptr, nullptr, nullptr, nullptr);
    k_gates<false><<<768, 256, 0, stream>>>(gxP, ghP, nullptr, nullptr, nullptr,
        bih2, bhh2, Hin + 2 * LH, Hout + 2 * LH);
    // o = (h2n*(1+gamma)+beta) @ Wo.T   (split-K=4)
    k_gemm<true, 0><<<dim3(4, 12, 4), 256, 0, stream>>>(Hout + 2 * LH, HID, Wo, HID, oP,
        HID, 192, PS_O, gamma, beta, nullptr, nullptr, nullptr, nullptr);
    k_sample<<<256, 256, 0, stream>>>(oP, embW, keys, t, cur, seq);
  }
}